// Round 2
// baseline (214.979 us; speedup 1.0000x reference)
//
#include <hip/hip_runtime.h>
#include <hip/hip_bf16.h>
#include <cstdint>

// Problem (all inputs/outputs fp32):
//   out[8192][2048] = X[8192][2048] @ Weff[2048][2048]
//   Weff[k][n] = W[k][n] + SCALE * sum_r A[k][r]*Bk[r][n], SCALE = 4/4 = 1.0
//
// Pipeline:
//   cvt_x  : fp32 X -> bf16 Xb (d_ws, 32MB)
//   prep_wt: fp32 (W + A@Bk)^T -> bf16 Wt [N][K] (d_ws+32MB, 8MB)
//   gemm_bt: m97-structure bf16 GEMM (128x128 tile, BK=32,
//            mfma_f32_16x16x32_bf16, global_load_lds width=16), fp32 out.

using bf16 = __hip_bfloat16;
typedef __attribute__((ext_vector_type(8))) __bf16 bf16x8;
typedef __attribute__((ext_vector_type(4))) float f32x4;

constexpr int Mdim = 8192;   // B*S
constexpr int Ndim = 2048;   // NH*HD
constexpr int Kdim = 2048;   // H
constexpr float SCALE = 1.0f;  // ALPHA/RANK = 4/4

constexpr int BM = 128, BN = 128, BK = 32;

__device__ __forceinline__ void gload_lds16(const void* g, void* l) {
  __builtin_amdgcn_global_load_lds(
      (const __attribute__((address_space(1))) uint32_t*)g,
      (__attribute__((address_space(3))) uint32_t*)l,
      16, 0, 0);
}

// ---------------- cvt_x: fp32 -> bf16, 8 elems/thread ----------------
__global__ void cvt_x(const float4* __restrict__ X, uint16_t* __restrict__ Xb) {
  const int i = blockIdx.x * blockDim.x + threadIdx.x;  // one thread = 8 floats
  float4 a = X[i * 2 + 0];
  float4 b = X[i * 2 + 1];
  uint16_t o[8];
  o[0] = __bfloat16_as_ushort(__float2bfloat16(a.x));
  o[1] = __bfloat16_as_ushort(__float2bfloat16(a.y));
  o[2] = __bfloat16_as_ushort(__float2bfloat16(a.z));
  o[3] = __bfloat16_as_ushort(__float2bfloat16(a.w));
  o[4] = __bfloat16_as_ushort(__float2bfloat16(b.x));
  o[5] = __bfloat16_as_ushort(__float2bfloat16(b.y));
  o[6] = __bfloat16_as_ushort(__float2bfloat16(b.z));
  o[7] = __bfloat16_as_ushort(__float2bfloat16(b.w));
  *reinterpret_cast<uint4*>(Xb + (size_t)i * 8) = *reinterpret_cast<uint4*>(o);
}

// ---------------- prep: Weff^T = (W + A@Bk)^T, [N][K] bf16 ----------------
__global__ void prep_wt(const float* __restrict__ W, const float* __restrict__ A,
                        const float* __restrict__ Bk, uint16_t* __restrict__ Wt) {
  __shared__ float tile[64][65];  // [n_local][k_local], +1 pad kills conflicts
  const int tx = threadIdx.x & 63;   // along N on load, along K on store
  const int ty = threadIdx.x >> 6;   // 0..3
  const int n0 = blockIdx.x * 64, k0 = blockIdx.y * 64;

  const int n = n0 + tx;
  const float b0 = Bk[0 * Ndim + n];
  const float b1 = Bk[1 * Ndim + n];
  const float b2 = Bk[2 * Ndim + n];
  const float b3 = Bk[3 * Ndim + n];

  for (int i = ty; i < 64; i += 4) {
    const int k = k0 + i;
    float w = W[(size_t)k * Ndim + n];
    w += SCALE * (A[k * 4 + 0] * b0 + A[k * 4 + 1] * b1 +
                  A[k * 4 + 2] * b2 + A[k * 4 + 3] * b3);
    tile[tx][i] = w;                       // transposed into LDS
  }
  __syncthreads();
  for (int i = ty; i < 64; i += 4) {
    Wt[(size_t)(n0 + i) * Kdim + (k0 + tx)] =
        __bfloat16_as_ushort(__float2bfloat16(tile[i][tx]));
  }
}

// ---------------- main GEMM: C = Xb @ Weff (Wt is Weff^T, K-major) --------
__global__ void gemm_bt(const uint16_t* __restrict__ X,
                        const uint16_t* __restrict__ Wt,
                        float* __restrict__ out) {
  __shared__ uint16_t As[BM * BK];  // [128][32] K-major, no pad (global_load_lds)
  __shared__ uint16_t Bs[BN * BK];  // [128][32] K-major

  const int t = threadIdx.x;
  const int wave = t >> 6, lane = t & 63;
  const int m0 = blockIdx.y * BM, n0 = blockIdx.x * BN;

  const int wm = wave & 1, wn = wave >> 1;  // 2x2 wave grid, 64x64 each
  const int l15 = lane & 15, kg = lane >> 4;

  // staging: each wave stages 2 chunks of A and 2 of B (chunk = 16 rows x 32)
  const int srow = lane >> 2;          // 0..15 row within chunk
  const int scol = (lane & 3) * 8;     // element col within row (8 bf16 = 16B)
  const uint16_t* Ag = X + (size_t)m0 * Kdim;
  const uint16_t* Bg = Wt + (size_t)n0 * Kdim;

  f32x4 acc[4][4] = {};

  for (int kt = 0; kt < Kdim; kt += BK) {
#pragma unroll
    for (int c = 0; c < 2; ++c) {
      const int chunk = wave * 2 + c;        // 0..7
      const int r = chunk * 16 + srow;       // tile-local row
      gload_lds16(Ag + (size_t)r * Kdim + kt + scol, &As[chunk * 512]);
      gload_lds16(Bg + (size_t)r * Kdim + kt + scol, &Bs[chunk * 512]);
    }
    __syncthreads();  // drains vmcnt -> tiles visible

    bf16x8 af[4], bfr[4];
#pragma unroll
    for (int i = 0; i < 4; ++i) {
      af[i]  = *reinterpret_cast<const bf16x8*>(&As[(wm * 64 + i * 16 + l15) * BK + kg * 8]);
      bfr[i] = *reinterpret_cast<const bf16x8*>(&Bs[(wn * 64 + i * 16 + l15) * BK + kg * 8]);
    }
#pragma unroll
    for (int i = 0; i < 4; ++i)
#pragma unroll
      for (int j = 0; j < 4; ++j)
        acc[i][j] = __builtin_amdgcn_mfma_f32_16x16x32_bf16(af[i], bfr[j], acc[i][j], 0, 0, 0);
    __syncthreads();  // before next stage overwrites tiles
  }

  // epilogue: C/D layout col = lane&15, row = (lane>>4)*4 + reg  [m89/m91]
#pragma unroll
  for (int i = 0; i < 4; ++i) {
    const int m_base = m0 + wm * 64 + i * 16 + kg * 4;
#pragma unroll
    for (int j = 0; j < 4; ++j) {
      const int n = n0 + wn * 64 + j * 16 + l15;
#pragma unroll
      for (int r = 0; r < 4; ++r) {
        out[(size_t)(m_base + r) * Ndim + n] = acc[i][j][r];
      }
    }
  }
}

extern "C" void kernel_launch(void* const* d_in, const int* in_sizes, int n_in,
                              void* d_out, int out_size, void* d_ws, size_t ws_size,
                              hipStream_t stream) {
  const float* x  = (const float*)d_in[0];  // [4,2048,2048]
  const float* W  = (const float*)d_in[1];  // [2048,16,128]
  const float* A  = (const float*)d_in[2];  // [2048,4]
  const float* Bk = (const float*)d_in[3];  // [4,16,128]
  float* out = (float*)d_out;               // [4,2048,16,128] fp32

  uint16_t* Xb = (uint16_t*)d_ws;                               // 32 MB
  uint16_t* Wt = (uint16_t*)((char*)d_ws + (size_t)Mdim * Kdim * 2);  // 8 MB

  // X fp32 -> bf16 (8 elems/thread)
  const int n_elem = Mdim * Kdim;              // 16.7M
  cvt_x<<<n_elem / (256 * 8), 256, 0, stream>>>((const float4*)x, Xb);

  // Weff^T build
  dim3 g1(Ndim / 64, Kdim / 64);  // 32 x 32
  prep_wt<<<g1, 256, 0, stream>>>(W, A, Bk, Wt);

  // main GEMM
  dim3 g2(Ndim / BN, Mdim / BM);  // 16 x 64
  gemm_bt<<<g2, 256, 0, stream>>>(Xb, Wt, out);
}

// Round 3
// 202.069 us; speedup vs baseline: 1.0639x; 1.0639x over previous
//
#include <hip/hip_runtime.h>
#include <hip/hip_bf16.h>
#include <cstdint>

// Problem (all inputs/outputs fp32):
//   out[8192][2048] = X[8192][2048] @ Weff[2048][2048]
//   Weff[k][n] = W[k][n] + SCALE * sum_r A[k][r]*Bk[r][n], SCALE = 4/4 = 1.0
//
// Pipeline:
//   cvt_x  : fp32 X -> bf16 Xb (d_ws, 32MB)
//   prep_wt: fp32 (W + A@Bk)^T -> bf16 Wt [N][K] (d_ws+32MB, 8MB)
//   gemm_bt: 128x128 tile, BK=64 (32 barriers), mfma_f32_16x16x32_bf16,
//            global_load_lds width=16 with XOR-chunk swizzle (p = g ^ (row&7))
//            -> conflict-free ds_read_b128 frag reads. fp32 out.

using bf16 = __hip_bfloat16;
typedef __attribute__((ext_vector_type(8))) __bf16 bf16x8;
typedef __attribute__((ext_vector_type(4))) float f32x4;

constexpr int Mdim = 8192;   // B*S
constexpr int Ndim = 2048;   // NH*HD
constexpr int Kdim = 2048;   // H
constexpr float SCALE = 1.0f;  // ALPHA/RANK = 4/4

constexpr int BM = 128, BN = 128, BK = 64;

__device__ __forceinline__ void gload_lds16(const void* g, void* l) {
  __builtin_amdgcn_global_load_lds(
      (const __attribute__((address_space(1))) uint32_t*)g,
      (__attribute__((address_space(3))) uint32_t*)l,
      16, 0, 0);
}

// ---------------- cvt_x: fp32 -> bf16, 8 elems/thread ----------------
__global__ void cvt_x(const float4* __restrict__ X, uint16_t* __restrict__ Xb) {
  const int i = blockIdx.x * blockDim.x + threadIdx.x;  // one thread = 8 floats
  float4 a = X[i * 2 + 0];
  float4 b = X[i * 2 + 1];
  uint16_t o[8];
  o[0] = __bfloat16_as_ushort(__float2bfloat16(a.x));
  o[1] = __bfloat16_as_ushort(__float2bfloat16(a.y));
  o[2] = __bfloat16_as_ushort(__float2bfloat16(a.z));
  o[3] = __bfloat16_as_ushort(__float2bfloat16(a.w));
  o[4] = __bfloat16_as_ushort(__float2bfloat16(b.x));
  o[5] = __bfloat16_as_ushort(__float2bfloat16(b.y));
  o[6] = __bfloat16_as_ushort(__float2bfloat16(b.z));
  o[7] = __bfloat16_as_ushort(__float2bfloat16(b.w));
  *reinterpret_cast<uint4*>(Xb + (size_t)i * 8) = *reinterpret_cast<uint4*>(o);
}

// ---------------- prep: Weff^T = (W + A@Bk)^T, [N][K] bf16 ----------------
__global__ void prep_wt(const float* __restrict__ W, const float* __restrict__ A,
                        const float* __restrict__ Bk, uint16_t* __restrict__ Wt) {
  __shared__ float tile[64][65];  // [n_local][k_local], +1 pad kills conflicts
  const int tx = threadIdx.x & 63;   // along N on load, along K on store
  const int ty = threadIdx.x >> 6;   // 0..3
  const int n0 = blockIdx.x * 64, k0 = blockIdx.y * 64;

  const int n = n0 + tx;
  const float b0 = Bk[0 * Ndim + n];
  const float b1 = Bk[1 * Ndim + n];
  const float b2 = Bk[2 * Ndim + n];
  const float b3 = Bk[3 * Ndim + n];

  for (int i = ty; i < 64; i += 4) {
    const int k = k0 + i;
    float w = W[(size_t)k * Ndim + n];
    w += SCALE * (A[k * 4 + 0] * b0 + A[k * 4 + 1] * b1 +
                  A[k * 4 + 2] * b2 + A[k * 4 + 3] * b3);
    tile[tx][i] = w;                       // transposed into LDS
  }
  __syncthreads();
  for (int i = ty; i < 64; i += 4) {
    Wt[(size_t)(n0 + i) * Kdim + (k0 + tx)] =
        __bfloat16_as_ushort(__float2bfloat16(tile[i][tx]));
  }
}

// ---------------- main GEMM: C = Xb @ Weff (Wt is Weff^T, K-major) --------
// LDS layout: As/Bs [128 rows][8 chunks of 16B]; physical chunk p at row r
// holds global chunk p ^ (r&7)  (swizzle applied via staging SOURCE address).
__global__ void gemm_bt(const uint16_t* __restrict__ X,
                        const uint16_t* __restrict__ Wt,
                        float* __restrict__ out) {
  __shared__ uint16_t As[BM * BK];  // 16 KB
  __shared__ uint16_t Bs[BN * BK];  // 16 KB

  const int t = threadIdx.x;
  const int wave = t >> 6, lane = t & 63;
  const int m0 = blockIdx.y * BM, n0 = blockIdx.x * BN;

  const int wm = wave & 1, wn = wave >> 1;  // 2x2 wave grid, 64x64 each
  const int l15 = lane & 15, kg = lane >> 4;
  const int sw = l15 & 7;                   // frag-read row swizzle key

  // staging: chunk = 8 rows x 64 cols (1 KB). 16 chunks per matrix.
  // lane -> row within chunk = lane>>3, physical 16B col = lane&7,
  // global 16B col = (lane&7) ^ (lane>>3)   [the XOR swizzle]
  const int r8 = lane >> 3;                 // 0..7
  const int gc = (lane & 7) ^ r8;           // swizzled global chunk col
  const uint16_t* Ag = X + (size_t)m0 * Kdim;
  const uint16_t* Bg = Wt + (size_t)n0 * Kdim;

  f32x4 acc[4][4] = {};

  for (int kt = 0; kt < Kdim; kt += BK) {
#pragma unroll
    for (int c = 0; c < 4; ++c) {
      const int ch = wave * 4 + c;          // 0..15
      const int row = ch * 8 + r8;          // tile-local row
      gload_lds16(Ag + (size_t)row * Kdim + kt + gc * 8, &As[ch * 512]);
      gload_lds16(Bg + (size_t)row * Kdim + kt + gc * 8, &Bs[ch * 512]);
    }
    __syncthreads();  // drains vmcnt -> tiles visible

#pragma unroll
    for (int s = 0; s < 2; ++s) {           // two 16x16x32 k-steps per BK=64
      bf16x8 af[4], bfr[4];
      const int p = (s * 4 + kg) ^ sw;      // physical chunk for logical k-chunk
#pragma unroll
      for (int i = 0; i < 4; ++i) {
        const int ra = wm * 64 + i * 16 + l15;
        const int rb = wn * 64 + i * 16 + l15;
        af[i]  = *reinterpret_cast<const bf16x8*>(&As[ra * BK + p * 8]);
        bfr[i] = *reinterpret_cast<const bf16x8*>(&Bs[rb * BK + p * 8]);
      }
#pragma unroll
      for (int i = 0; i < 4; ++i)
#pragma unroll
        for (int j = 0; j < 4; ++j)
          acc[i][j] = __builtin_amdgcn_mfma_f32_16x16x32_bf16(af[i], bfr[j], acc[i][j], 0, 0, 0);
    }
    __syncthreads();  // before next stage overwrites tiles
  }

  // epilogue: C/D layout col = lane&15, row = (lane>>4)*4 + reg  [m89/m91]
#pragma unroll
  for (int i = 0; i < 4; ++i) {
    const int m_base = m0 + wm * 64 + i * 16 + kg * 4;
#pragma unroll
    for (int j = 0; j < 4; ++j) {
      const int n = n0 + wn * 64 + j * 16 + l15;
#pragma unroll
      for (int r = 0; r < 4; ++r) {
        out[(size_t)(m_base + r) * Ndim + n] = acc[i][j][r];
      }
    }
  }
}

extern "C" void kernel_launch(void* const* d_in, const int* in_sizes, int n_in,
                              void* d_out, int out_size, void* d_ws, size_t ws_size,
                              hipStream_t stream) {
  const float* x  = (const float*)d_in[0];  // [4,2048,2048]
  const float* W  = (const float*)d_in[1];  // [2048,16,128]
  const float* A  = (const float*)d_in[2];  // [2048,4]
  const float* Bk = (const float*)d_in[3];  // [4,16,128]
  float* out = (float*)d_out;               // [4,2048,16,128] fp32

  uint16_t* Xb = (uint16_t*)d_ws;                               // 32 MB
  uint16_t* Wt = (uint16_t*)((char*)d_ws + (size_t)Mdim * Kdim * 2);  // 8 MB

  // X fp32 -> bf16 (8 elems/thread)
  const int n_elem = Mdim * Kdim;              // 16.7M
  cvt_x<<<n_elem / (256 * 8), 256, 0, stream>>>((const float4*)x, Xb);

  // Weff^T build
  dim3 g1(Ndim / 64, Kdim / 64);  // 32 x 32
  prep_wt<<<g1, 256, 0, stream>>>(W, A, Bk, Wt);

  // main GEMM
  dim3 g2(Ndim / BN, Mdim / BM);  // 16 x 64
  gemm_bt<<<g2, 256, 0, stream>>>(Xb, Wt, out);
}